// Round 1
// baseline (227.385 us; speedup 1.0000x reference)
//
#include <hip/hip_runtime.h>
#include <math.h>

// Problem constants (match reference)
#define B 32
#define C 4
#define H 360
#define W 640
#define P (H*W)            // 230400 pixels per batch
#define L 5                // MAX_LANES
#define DELTA_V 1.0f
#define DELTA_D 6.0f

#define NV 25              // per-block partial values: 20 sums (5 lanes x 4 ch) + 5 counts
#define BLK1 32            // blocks per batch for the streaming kernels
#define NBLK (B*BLK1)      // 1024 total blocks
#define G4 (P/4)           // 57600 float4/int4 groups per batch

__device__ __forceinline__ float waveReduce(float v) {
#pragma unroll
    for (int off = 32; off; off >>= 1) v += __shfl_down(v, off, 64);
    return v;
}

// ---------------------------------------------------------------------------
// Kernel 1: per-(batch,lane) segment sums + counts, deterministic block partials
// ---------------------------------------------------------------------------
__global__ __launch_bounds__(256) void seg_sums_k(const int* __restrict__ tgt,
                                                  const float* __restrict__ emb,
                                                  float* __restrict__ part1) {
    const int b = blockIdx.y;
    float s[L][C];
    float cn[L];
#pragma unroll
    for (int l = 0; l < L; ++l) {
        cn[l] = 0.f;
#pragma unroll
        for (int c = 0; c < C; ++c) s[l][c] = 0.f;
    }

    const int4*   t4 = (const int4*)(tgt + (size_t)b * P);
    const float4* e0 = (const float4*)(emb + (size_t)(b*C + 0) * P);
    const float4* e1 = (const float4*)(emb + (size_t)(b*C + 1) * P);
    const float4* e2 = (const float4*)(emb + (size_t)(b*C + 2) * P);
    const float4* e3 = (const float4*)(emb + (size_t)(b*C + 3) * P);

    auto proc = [&](int tt, float x0, float x1, float x2, float x3) {
#pragma unroll
        for (int l = 0; l < L; ++l) {
            float m = (tt == l + 1) ? 1.0f : 0.0f;
            cn[l] += m;
            s[l][0] = fmaf(m, x0, s[l][0]);
            s[l][1] = fmaf(m, x1, s[l][1]);
            s[l][2] = fmaf(m, x2, s[l][2]);
            s[l][3] = fmaf(m, x3, s[l][3]);
        }
    };

    for (int g = blockIdx.x * 256 + threadIdx.x; g < G4; g += BLK1 * 256) {
        int4   t  = t4[g];
        float4 a0 = e0[g], a1 = e1[g], a2 = e2[g], a3 = e3[g];
        proc(t.x, a0.x, a1.x, a2.x, a3.x);
        proc(t.y, a0.y, a1.y, a2.y, a3.y);
        proc(t.z, a0.z, a1.z, a2.z, a3.z);
        proc(t.w, a0.w, a1.w, a2.w, a3.w);
    }

    // pack 25 values, wave-reduce each, then cross-wave via LDS
    float vals[NV];
#pragma unroll
    for (int l = 0; l < L; ++l) {
#pragma unroll
        for (int c = 0; c < C; ++c) vals[l*4 + c] = s[l][c];
        vals[20 + l] = cn[l];
    }

    __shared__ float red[4][NV];
    const int lane = threadIdx.x & 63, wave = threadIdx.x >> 6;
#pragma unroll
    for (int k = 0; k < NV; ++k) {
        float r = waveReduce(vals[k]);
        if (lane == 0) red[wave][k] = r;
    }
    __syncthreads();
    if (threadIdx.x < NV) {
        float r = red[0][threadIdx.x] + red[1][threadIdx.x]
                + red[2][threadIdx.x] + red[3][threadIdx.x];
        part1[(size_t)(b * BLK1 + blockIdx.x) * NV + threadIdx.x] = r;
    }
}

// ---------------------------------------------------------------------------
// Kernel 2: reduce partials -> means/valid/point_count, and the push loss
// ---------------------------------------------------------------------------
__global__ __launch_bounds__(256) void finalize_k(const float* __restrict__ part1,
                                                  float* __restrict__ means,
                                                  float* __restrict__ validf,
                                                  float* __restrict__ misc) {
    __shared__ float smean[B*L*C];
    __shared__ float svalid[B*L];
    __shared__ float lred[4];
    const int tid = threadIdx.x;
    const int lane = tid & 63, wave = tid >> 6;

    float pc = 0.f;
    if (tid < B*L) {
        const int b = tid / L, l = tid % L;
        float sm[C] = {0.f, 0.f, 0.f, 0.f};
        float cnt = 0.f;
        for (int blk = 0; blk < BLK1; ++blk) {
            const float* p = part1 + (size_t)(b * BLK1 + blk) * NV;
#pragma unroll
            for (int c = 0; c < C; ++c) sm[c] += p[l*4 + c];
            cnt += p[20 + l];
        }
        const float inv = 1.0f / fmaxf(cnt, 1.0f);
        const bool  v   = cnt > 1.5f;   // integer count > 1
#pragma unroll
        for (int c = 0; c < C; ++c) {
            float m = sm[c] * inv;
            smean[tid*C + c] = m;
            means[tid*C + c] = m;
        }
        svalid[tid] = v ? 1.f : 0.f;
        validf[tid] = v ? 1.f : 0.f;
        if (v) pc = cnt;
    }

    // block-reduce point_count
    {
        float r = waveReduce(pc);
        if (lane == 0) lred[wave] = r;
    }
    __syncthreads();
    if (tid == 0) misc[1] = lred[0] + lred[1] + lred[2] + lred[3];

    // push (distance) loss: one thread per batch, pairs i<j of valid means
    float vb = 0.f, has = 0.f;
    if (tid < B) {
        const int base = tid * L;
        float ssum = 0.f, np = 0.f;
#pragma unroll
        for (int i = 0; i < L; ++i) {
#pragma unroll
            for (int j = i + 1; j < L; ++j) {
                float ok = svalid[base+i] * svalid[base+j];
                float d0 = smean[(base+i)*C+0] - smean[(base+j)*C+0];
                float d1 = smean[(base+i)*C+1] - smean[(base+j)*C+1];
                float d2 = smean[(base+i)*C+2] - smean[(base+j)*C+2];
                float d3 = smean[(base+i)*C+3] - smean[(base+j)*C+3];
                float psq = d0*d0 + d1*d1 + d2*d2 + d3*d3;
                float pd  = sqrtf(fmaxf(psq, 1e-12f));
                float ph  = fmaxf(DELTA_D - pd, 0.f);
                ssum += ok * ph * ph;
                np   += ok;
            }
        }
        if (np > 0.f) { vb = ssum / np; has = 1.f; }
    }
    if (wave == 0) {   // all nonzero contributions live in lanes 0..31 of wave 0
        float vr = waveReduce(vb);
        float hr = waveReduce(has);
        if (tid == 0) misc[0] = (hr > 0.f) ? vr / hr : 0.f;
    }
}

// ---------------------------------------------------------------------------
// Kernel 3: pull (variance) loss — per-pixel hinge distance to its lane mean
// ---------------------------------------------------------------------------
__global__ __launch_bounds__(256) void pull_k(const int* __restrict__ tgt,
                                              const float* __restrict__ emb,
                                              const float* __restrict__ means,
                                              const float* __restrict__ validf,
                                              float* __restrict__ part3) {
    __shared__ float4 lmean[L + 1];   // lane 0 -> zero mean
    __shared__ float  lvalid[L + 1];  // lane 0 -> invalid
    __shared__ float  lred[4];
    const int b = blockIdx.y;
    const int tid = threadIdx.x;

    if (tid == 0) { lmean[0] = make_float4(0.f, 0.f, 0.f, 0.f); lvalid[0] = 0.f; }
    else if (tid <= L) {
        lmean[tid]  = *(const float4*)(means + ((size_t)b*L + (tid-1)) * C);
        lvalid[tid] = validf[b*L + (tid-1)];
    }
    __syncthreads();

    const int4*   t4 = (const int4*)(tgt + (size_t)b * P);
    const float4* e0 = (const float4*)(emb + (size_t)(b*C + 0) * P);
    const float4* e1 = (const float4*)(emb + (size_t)(b*C + 1) * P);
    const float4* e2 = (const float4*)(emb + (size_t)(b*C + 2) * P);
    const float4* e3 = (const float4*)(emb + (size_t)(b*C + 3) * P);

    float acc = 0.f;
    auto proc = [&](int tt, float x0, float x1, float x2, float x3) {
        float4 m = lmean[tt];
        float d0 = x0 - m.x, d1 = x1 - m.y, d2 = x2 - m.z, d3 = x3 - m.w;
        float sq   = d0*d0 + d1*d1 + d2*d2 + d3*d3;
        float dist = sqrtf(fmaxf(sq, 1e-12f));
        float h    = fmaxf(dist - DELTA_V, 0.f);
        acc = fmaf(lvalid[tt] * h, h, acc);
    };

    for (int g = blockIdx.x * 256 + threadIdx.x; g < G4; g += BLK1 * 256) {
        int4   t  = t4[g];
        float4 a0 = e0[g], a1 = e1[g], a2 = e2[g], a3 = e3[g];
        proc(t.x, a0.x, a1.x, a2.x, a3.x);
        proc(t.y, a0.y, a1.y, a2.y, a3.y);
        proc(t.z, a0.z, a1.z, a2.z, a3.z);
        proc(t.w, a0.w, a1.w, a2.w, a3.w);
    }

    float r = waveReduce(acc);
    const int lane = tid & 63, wave = tid >> 6;
    if (lane == 0) lred[wave] = r;
    __syncthreads();
    if (tid == 0)
        part3[b * BLK1 + blockIdx.x] = lred[0] + lred[1] + lred[2] + lred[3];
}

// ---------------------------------------------------------------------------
// Kernel 4: final combine
// ---------------------------------------------------------------------------
__global__ __launch_bounds__(256) void finish_k(const float* __restrict__ part3,
                                                const float* __restrict__ misc,
                                                float* __restrict__ out) {
    __shared__ float lred[4];
    const int tid = threadIdx.x;
    float s = 0.f;
    for (int i = tid; i < NBLK; i += 256) s += part3[i];
    float r = waveReduce(s);
    const int lane = tid & 63, wave = tid >> 6;
    if (lane == 0) lred[wave] = r;
    __syncthreads();
    if (tid == 0) {
        float ds  = lred[0] + lred[1] + lred[2] + lred[3];
        float pcv = misc[1];
        float dl  = (pcv > 0.f) ? ds / fmaxf(pcv, 1.0f) : 0.f;
        out[0] = dl + misc[0];   // dist_loss + var_loss
    }
}

// ---------------------------------------------------------------------------
extern "C" void kernel_launch(void* const* d_in, const int* in_sizes, int n_in,
                              void* d_out, int out_size, void* d_ws, size_t ws_size,
                              hipStream_t stream) {
    const int*   tgt = (const int*)d_in[0];    // targets int32 [B,H,W]
    const float* emb = (const float*)d_in[1];  // embedding fp32 [B,C,H,W]

    float* ws     = (float*)d_ws;
    float* part1  = ws;                        // NBLK*NV = 25600 floats
    float* means  = part1 + (size_t)NBLK * NV; // 640 floats (16B-aligned: 25600*4 % 16 == 0)
    float* validf = means + B*L*C;             // 160 floats
    float* misc   = validf + B*L;              // 4 floats ([0]=var_loss, [1]=point_count)
    float* part3  = misc + 4;                  // NBLK floats
    // total ws use: ~110 KB

    dim3 grid(BLK1, B);
    seg_sums_k<<<grid, 256, 0, stream>>>(tgt, emb, part1);
    finalize_k<<<1, 256, 0, stream>>>(part1, means, validf, misc);
    pull_k<<<grid, 256, 0, stream>>>(tgt, emb, means, validf, part3);
    finish_k<<<1, 256, 0, stream>>>(part3, misc, (float*)d_out);
}